// Round 5
// baseline (155.020 us; speedup 1.0000x reference)
//
#include <hip/hip_runtime.h>

// CostVolume: x,y fp32 [2,64,96,320]; GROUP=8 -> 16 (b,g) slabs x 8 channels.
// cost[bg,d,h,j] = sum_cc | xn[cc,j] - (j>=d ? yn[cc,j-d] : 0) |,
// xn/yn per-pixel channel-L2-normalized (norm + 1e-5). Out [2,8,49,96,320] f32.
//
// R5 = R4 with cc-OUTER Phase B:
//  - lane l of wave w: quad q = w*16+(l&15), chunk dc = l>>4 (groups g=3dc+gi).
//  - Per channel cc: ONE batch of 6 aligned ds_read_b128 (4 consecutive window
//    quads W..W+3 with W=q-3dc-3, the d=48 quad q-12, and xq quad Q) feeds all
//    52 accumulators (3 groups x 16 + 4 for d48). DS/thread 64 -> 48; xq
//    register block 32 -> 4 (only current cc live) to kill R4's pressure
//    (VGPR_Count=64 with ~70+ live values => spill/remat churn).
//  - acc[3][4][4] + acc48 + sA live across cc loop (~52 regs); stores are a
//    dependency-free float4 burst at the end.
//  - Left-pad boundary (j<d): clamped window reads feed only lanes whose
//    result is overridden by sA = sum|xn| (verified exact in R4, absmax 0).

#define HH    96
#define WW    320
#define HW    (HH * WW)      // 30720
#define NDISP 49
#define EPSN  1e-5f

__global__ __launch_bounds__(WW, 4) void cost_volume_kernel(
    const float* __restrict__ x, const float* __restrict__ y,
    float* __restrict__ out)
{
    __shared__ float xn_s[8][WW];
    __shared__ float yn_s[8][WW];

    const int t   = threadIdx.x;     // 0..319
    const int blk = blockIdx.x;      // 0..1535
    const int h   = blk % HH;
    const int bg  = blk / HH;        // 0..15

    const size_t base = (size_t)bg * 8 * HW + (size_t)h * WW;

    // ---- Phase A: thread t normalizes column t, stages channel-major ----
    {
        float xv[8], yv[8];
        float xs = 0.f, ys = 0.f;
#pragma unroll
        for (int cc = 0; cc < 8; ++cc) {
            float xi = x[base + (size_t)cc * HW + t];
            float yi = y[base + (size_t)cc * HW + t];
            xv[cc] = xi; yv[cc] = yi;
            xs += xi * xi;
            ys += yi * yi;
        }
        const float xinv = 1.f / (sqrtf(xs) + EPSN);
        const float yinv = 1.f / (sqrtf(ys) + EPSN);
#pragma unroll
        for (int cc = 0; cc < 8; ++cc) {
            xn_s[cc][t] = xv[cc] * xinv;
            yn_s[cc][t] = yv[cc] * yinv;
        }
    }
    __syncthreads();

    // ---- Phase B ----
    const int l  = t & 63;
    const int q  = (t >> 6) * 16 + (l & 15);   // 0..79
    const int dc = l >> 4;                     // 0..3
    const int Q  = 4 * q;
    const int W  = q - 3 * dc - 3;             // lowest window quad

    // clamped window addresses (clamped reads only feed overridden lanes)
    int a[4];
#pragma unroll
    for (int k = 0; k < 4; ++k) {
        int wq = W + k; if (wq < 0) wq = 0;
        a[k] = 4 * wq;
    }
    int wq48 = q - 12; if (wq48 < 0) wq48 = 0;
    const int a48 = 4 * wq48;

    float acc[3][4][4];   // [gi][e][k] : d = 4*(3dc+gi)+e, column Q+k
#pragma unroll
    for (int gi = 0; gi < 3; ++gi)
#pragma unroll
        for (int e = 0; e < 4; ++e)
#pragma unroll
            for (int k = 0; k < 4; ++k) acc[gi][e][k] = 0.f;
    float acc48[4] = {0.f, 0.f, 0.f, 0.f};
    float sA[4]    = {0.f, 0.f, 0.f, 0.f};

#pragma unroll
    for (int cc = 0; cc < 8; ++cc) {
        const float* row = yn_s[cc];
        const float4 w0 = *(const float4*)&row[a[0]];
        const float4 w1 = *(const float4*)&row[a[1]];
        const float4 w2 = *(const float4*)&row[a[2]];
        const float4 w3 = *(const float4*)&row[a[3]];
        const float4 w4 = *(const float4*)&row[a48];
        const float4 xc = *(const float4*)&xn_s[cc][Q];

        const float wf[16] = { w0.x, w0.y, w0.z, w0.w,
                               w1.x, w1.y, w1.z, w1.w,
                               w2.x, w2.y, w2.z, w2.w,
                               w3.x, w3.y, w3.z, w3.w };
        const float xk[4] = { xc.x, xc.y, xc.z, xc.w };

#pragma unroll
        for (int k = 0; k < 4; ++k) sA[k] += fabsf(xk[k]);

#pragma unroll
        for (int gi = 0; gi < 3; ++gi) {
            // group g = 3dc+gi uses quads (q-g-1, q-g) = local quads (2-gi, 3-gi)
            const int b0 = (2 - gi) * 4;
#pragma unroll
            for (int e = 0; e < 4; ++e)
#pragma unroll
                for (int k = 0; k < 4; ++k)
                    acc[gi][e][k] += fabsf(xk[k] - wf[b0 + k + 4 - e]);
        }
        // d = 48: yn col Q+k-48 = elem k of quad q-12
        acc48[0] += fabsf(xk[0] - w4.x);
        acc48[1] += fabsf(xk[1] - w4.y);
        acc48[2] += fabsf(xk[2] - w4.z);
        acc48[3] += fabsf(xk[3] - w4.w);
    }

    // ---- Store burst ----
    float* outp = out + (size_t)bg * (NDISP * HW) + (size_t)h * WW + Q;

#pragma unroll
    for (int gi = 0; gi < 3; ++gi) {
#pragma unroll
        for (int e = 0; e < 4; ++e) {
            const int d = 4 * (3 * dc + gi) + e;   // 0..47
            float4 rr;
            rr.x = (Q + 0 < d) ? sA[0] : acc[gi][e][0];
            rr.y = (Q + 1 < d) ? sA[1] : acc[gi][e][1];
            rr.z = (Q + 2 < d) ? sA[2] : acc[gi][e][2];
            rr.w = (Q + 3 < d) ? sA[3] : acc[gi][e][3];
            *(float4*)&outp[(size_t)d * HW] = rr;
        }
    }
    {
        float4 rr;
        rr.x = (Q + 0 < 48) ? sA[0] : acc48[0];
        rr.y = (Q + 1 < 48) ? sA[1] : acc48[1];
        rr.z = (Q + 2 < 48) ? sA[2] : acc48[2];
        rr.w = (Q + 3 < 48) ? sA[3] : acc48[3];
        if (dc == 0)
            *(float4*)&outp[(size_t)48 * HW] = rr;
    }
}

extern "C" void kernel_launch(void* const* d_in, const int* in_sizes, int n_in,
                              void* d_out, int out_size, void* d_ws, size_t ws_size,
                              hipStream_t stream) {
    const float* x = (const float*)d_in[0];
    const float* y = (const float*)d_in[1];
    float* out = (float*)d_out;
    dim3 grid(16 * HH);   // 1536 blocks: one per (b,g,h) row -> 6/CU balanced
    dim3 block(WW);       // 320 threads = 5 waves
    cost_volume_kernel<<<grid, block, 0, stream>>>(x, y, out);
}